// Round 16
// baseline (126.085 us; speedup 1.0000x reference)
//
#include <hip/hip_runtime.h>
#include <cstdint>

#define NA_N 50000
#define NB_N 50000
#define NE_N 800000
#define DD 256
#define GEMM_NBLK 782            // (NB_N+63)/64
#define WT_NBLK   32
#define RS_NBLK   3125           // (NE_N+255)/256
#define SA_NBLK   3125           // (NA_N+15)/16

using bf8   = __attribute__((ext_vector_type(8))) short;   // 8 bf16 = 4 VGPR
using f32x4 = __attribute__((ext_vector_type(4))) float;
using u16x8 = __attribute__((ext_vector_type(8))) ushort;

__device__ __forceinline__ ushort f2bf(float f) {
    uint u = __float_as_uint(f);
    uint r = (u + 0x7fffu + ((u >> 16) & 1u)) >> 16;       // RNE
    return (ushort)r;
}
__device__ __forceinline__ float bf2f(ushort u) {
    return __uint_as_float(((uint)u) << 16);
}

// ------- prep (zero LDS -> full occupancy for streaming blocks) -------
// blocks 0-31:      Wt[n][k] = bf16(W[k][n])
// 32..3156:         row_start[] from sorted esrc
// 3157..6281:       s_a[i] = dot(fa[i,:], a_top)   (51 MB stream at HBM BW)
// 6282:             w2[k] = dot(W[k,:], a_bot) (fp32); c0 = dot(bias, a_bot)
__global__ __launch_bounds__(256) void prep_k(const float* __restrict__ W,
    ushort* __restrict__ Wt, const int* __restrict__ esrc,
    int* __restrict__ row_start, const float* __restrict__ fa,
    const float* __restrict__ a_top, float* __restrict__ s_a,
    const float* __restrict__ bias, const float* __restrict__ a_bot,
    float* __restrict__ w2c0)
{
    const int t = threadIdx.x;
    if (blockIdx.x < WT_NBLK) {                // ---- W transpose+cast, k-slab of 8 ----
        const int k0 = blockIdx.x * 8;
        u16x8 pack;
#pragma unroll
        for (int j = 0; j < 8; j++)
            pack[j] = f2bf(W[(size_t)(k0 + j) * DD + t]);   // coalesced across t
        *(u16x8*)(Wt + (size_t)t * DD + k0) = pack;         // Wt[n=t][k0..k0+7]
        return;
    }
    if (blockIdx.x < WT_NBLK + RS_NBLK) {      // ---- row_start builder ----
        int e = (blockIdx.x - WT_NBLK) * 256 + t;
        if (e >= NE_N) return;
        int s    = esrc[e];
        int prev = (e == 0) ? -1 : esrc[e - 1];
        for (int r = prev + 1; r <= s; r++) row_start[r] = e;
        if (e == NE_N - 1)
            for (int r = s + 1; r <= NA_N; r++) row_start[r] = NE_N;
        return;
    }
    if (blockIdx.x < WT_NBLK + RS_NBLK + SA_NBLK) {  // ---- s_a rowdot ----
        const int row = (blockIdx.x - WT_NBLK - RS_NBLK) * 16 + (t >> 4);
        if (row >= NA_N) return;
        const f32x4* fr = (const f32x4*)(fa + (size_t)row * DD) + (t & 15) * 4;
        const f32x4* tv = (const f32x4*)a_top + (t & 15) * 4;
        float p = 0.f;
#pragma unroll
        for (int j = 0; j < 4; j++) {
            f32x4 x = fr[j], y = tv[j];
            p += x[0] * y[0] + x[1] * y[1] + x[2] * y[2] + x[3] * y[3];
        }
        p += __shfl_xor(p, 1, 64); p += __shfl_xor(p, 2, 64);
        p += __shfl_xor(p, 4, 64); p += __shfl_xor(p, 8, 64);
        if ((t & 15) == 0) s_a[row] = p;
        return;
    }
    // ---- w2[k=t] = dot(W[t,:], a_bot)  (ROW dot — bugfix of r15); c0 = dot(bias,a_bot) ----
    {
        const f32x4* wr = (const f32x4*)(W + (size_t)t * DD);
        const f32x4* ab = (const f32x4*)a_bot;
        float acc = 0.f;
#pragma unroll 8
        for (int j = 0; j < 64; j++) {
            f32x4 x = wr[j], y = ab[j];
            acc += x[0] * y[0] + x[1] * y[1] + x[2] * y[2] + x[3] * y[3];
        }
        w2c0[t] = acc;
        if (t == 0) {
            float c0 = 0.f;
            for (int n = 0; n < DD; n++) c0 = fmaf(bias[n], a_bot[n], c0);
            w2c0[DD] = c0;
        }
    }
}

// ------- GEMM BM=64, LDS exactly 32 KB (5 blocks/CU): emb_b = bf16(fb)@W + bias -------
// s_b fused into STAGING via s_b = fb@w2 + c0 (fp32, pre-round).
// As unpadded [64][256] with T2 XOR swizzle (byte ^= (row&7)<<4) on write & read.
// B-frags register-pipelined 1 ks-step ahead.
__global__ __launch_bounds__(256) void gemm_mfma(
    const float* __restrict__ A, const ushort* __restrict__ Wt,
    const float* __restrict__ bias, const float* __restrict__ w2c0,
    ushort* __restrict__ C, float* __restrict__ s_b)
{
    __shared__ ushort As[64 * 256];            // 32768 B exactly
    const int t  = threadIdx.x;
    const int r0 = blockIdx.x * 64;
    const int wv = t >> 6;

    const f32x4 w2v = ((const f32x4*)w2c0)[t & 63];
    const float c0  = w2c0[DD];

#pragma unroll
    for (int i = 0; i < 16; i++) {
        int row = i * 4 + wv;                  // wave-uniform row per iteration
        int c4  = t & 63;
        int gr  = r0 + row; if (gr >= NB_N) gr = 0;       // clamp tail
        float4 v = ((const float4*)(A + (size_t)gr * DD))[c4];
        ushort4 b;
        b.x = f2bf(v.x); b.y = f2bf(v.y); b.z = f2bf(v.z); b.w = f2bf(v.w);
        uint o = (uint)(row * 512 + c4 * 8) ^ (uint)((row & 7) << 4);
        *(ushort4*)((char*)As + o) = b;
        // fused s_b partial: dot(fp32 row, w2), 64-lane reduce
        float p = v.x * w2v[0] + v.y * w2v[1] + v.z * w2v[2] + v.w * w2v[3];
        p += __shfl_xor(p, 1, 64);  p += __shfl_xor(p, 2, 64);
        p += __shfl_xor(p, 4, 64);  p += __shfl_xor(p, 8, 64);
        p += __shfl_xor(p, 16, 64); p += __shfl_xor(p, 32, 64);
        if ((t & 63) == 0 && r0 + row < NB_N) s_b[r0 + row] = p + c0;
    }
    __syncthreads();

    const int lane = t & 63;
    const int lr   = lane & 15;
    const int lkb  = ((lane >> 4) << 4);       // k-group byte offset within 64B
    const ushort* Wb = Wt + (size_t)(wv * 64 + lr) * DD + (lane >> 4) * 8;

    f32x4 acc[4][4];
#pragma unroll
    for (int m = 0; m < 4; m++)
#pragma unroll
        for (int n = 0; n < 4; n++) acc[m][n] = (f32x4){0.f, 0.f, 0.f, 0.f};

    bf8 bbc[4], bbn[4];
#pragma unroll
    for (int n = 0; n < 4; n++)                       // preload ks=0 B-frags
        bbc[n] = *(const bf8*)(Wb + (size_t)n * 16 * DD);

#pragma unroll
    for (int ks = 0; ks < 8; ks++) {
        if (ks < 7) {
#pragma unroll
            for (int n = 0; n < 4; n++)               // prefetch ks+1 B-frags
                bbn[n] = *(const bf8*)(Wb + (size_t)n * 16 * DD + ks * 32 + 32);
        }
        bf8 af[4];
#pragma unroll
        for (int m = 0; m < 4; m++) {
            int  row = m * 16 + lr;
            uint o   = (uint)(row * 512 + ks * 64 + lkb) ^ (uint)((row & 7) << 4);
            af[m] = *(const bf8*)((const char*)As + o);
        }
#pragma unroll
        for (int m = 0; m < 4; m++)
#pragma unroll
            for (int n = 0; n < 4; n++)
                acc[m][n] = __builtin_amdgcn_mfma_f32_16x16x32_bf16(
                    af[m], bbc[n], acc[m][n], 0, 0, 0);
#pragma unroll
        for (int n = 0; n < 4; n++) bbc[n] = bbn[n];  // static rotation
    }

#pragma unroll
    for (int m = 0; m < 4; m++)
#pragma unroll
        for (int n = 0; n < 4; n++) {
            int   col = wv * 64 + n * 16 + lr;
            float bv  = bias[col];
#pragma unroll
            for (int r = 0; r < 4; r++) {
                int rowg = r0 + m * 16 + (lane >> 4) * 4 + r;  // C: col=lane&15, row=(lane>>4)*4+r
                if (rowg < NB_N)
                    C[(size_t)rowg * DD + col] = f2bf(acc[m][n][r] + bv);
            }
        }
}

// -------- edge aggregation: wave/row, quarter-wave/edge, depth-2 software pipeline --------
__global__ __launch_bounds__(256) void edge_agg8(
    const int* __restrict__ edst, const int* __restrict__ row_start,
    const float* __restrict__ s_a, const float* __restrict__ sb,
    const ushort* __restrict__ emb, float* __restrict__ out)
{
    const int lane = threadIdx.x & 63;
    const int a    = blockIdx.x * 4 + (threadIdx.x >> 6);
    if (a >= NA_N) return;

    const float sa_a = s_a[a];
    const int g = lane >> 4;          // quarter-wave group: one edge per stage
    const int c = lane & 15;          // 16-col block within row
    const int beg = row_start[a], end = row_start[a + 1];

    float accA[8], accB[8];
#pragma unroll
    for (int j = 0; j < 8; j++) { accA[j] = 0.f; accB[j] = 0.f; }
    float rs = 0.f;

    if (beg < end) {
        const int last = end - 1;

        int   pc  = beg + g;                      // current-stage position
        int   pn  = pc + 4;                       // next-stage position
        int   dc  = edst[min(pc, last)];
        int   dn  = edst[min(pn, last)];
        float sbc = sb[dc];
        float sbn = sb[dn];
        const ushort* rc = emb + (size_t)dc * DD + c * 16;
        u16x8 ua = *(const u16x8*)rc;             // stage-0 gathers in flight
        u16x8 ub = *(const u16x8*)(rc + 8);

#pragma unroll 2
        for (int e = beg; e < end; e += 4) {
            // issue next-stage gathers (independent of current consumption)
            const ushort* rn = emb + (size_t)dn * DD + c * 16;
            u16x8 na = *(const u16x8*)rn;
            u16x8 nb = *(const u16x8*)(rn + 8);
            // preload stage+2 index & sb
            int   p2  = pn + 4;
            int   d2  = edst[min(p2, last)];
            float sb2 = sb[d2];

            // score for current stage
            float lg = sa_a + sbc;
            float el = lg > 0.f ? lg : 0.1f * (__expf(lg) - 1.f);
            float s  = (pc < end) ? __expf(el) : 0.f;

            // consume current gathers (waits only on ua/ub — older loads)
#pragma unroll
            for (int j = 0; j < 8; j++) {
                accA[j] = fmaf(s, bf2f(ua[j]), accA[j]);
                accB[j] = fmaf(s, bf2f(ub[j]), accB[j]);
            }
            rs += s;

            // rotate pipeline (pure renaming after unroll)
            pc = pn;  dc = dn;  sbc = sbn;
            ua = na;  ub = nb;
            pn = p2;  dn = d2;  sbn = sb2;
        }
    }

    // combine the 4 quarter-wave partials (xor over group bits 16,32)
#pragma unroll
    for (int j = 0; j < 8; j++) {
        accA[j] += __shfl_xor(accA[j], 16, 64);
        accA[j] += __shfl_xor(accA[j], 32, 64);
        accB[j] += __shfl_xor(accB[j], 16, 64);
        accB[j] += __shfl_xor(accB[j], 32, 64);
    }
    rs += __shfl_xor(rs, 16, 64);
    rs += __shfl_xor(rs, 32, 64);

    if (g == 0) {                      // lanes 0-15 write cols c*16..c*16+15
        const float inv = (rs == 0.f) ? 1.f : (1.f / rs);
        float* op = out + (size_t)a * DD + c * 16;
        float4 o0 = { accA[0] * inv, accA[1] * inv, accA[2] * inv, accA[3] * inv };
        float4 o1 = { accA[4] * inv, accA[5] * inv, accA[6] * inv, accA[7] * inv };
        float4 o2 = { accB[0] * inv, accB[1] * inv, accB[2] * inv, accB[3] * inv };
        float4 o3 = { accB[4] * inv, accB[5] * inv, accB[6] * inv, accB[7] * inv };
        *(float4*)(op + 0)  = o0;
        *(float4*)(op + 4)  = o1;
        *(float4*)(op + 8)  = o2;
        *(float4*)(op + 12) = o3;
    }
}

extern "C" void kernel_launch(void* const* d_in, const int* in_sizes, int n_in,
                              void* d_out, int out_size, void* d_ws, size_t ws_size,
                              hipStream_t stream)
{
    const float* fa   = (const float*)d_in[0];
    const float* fb   = (const float*)d_in[1];
    const float* W    = (const float*)d_in[2];
    const float* bias = (const float*)d_in[3];
    const float* avec = (const float*)d_in[4];
    const int*   esrc = (const int*)d_in[5];
    const int*   edst = (const int*)d_in[6];
    float*       out  = (float*)d_out;

    char*   ws        = (char*)d_ws;
    ushort* emb_b     = (ushort*)ws;                               // 25.6 MB
    float*  s_b       = (float*)(ws + (size_t)NB_N * DD * 2);      // NB
    int*    row_start = (int*)(s_b + NB_N);                        // NA+1
    float*  s_a       = (float*)(row_start + NA_N + 2);            // NA
    float*  w2c0      = s_a + NA_N;                                // 257
    ushort* Wt        = (ushort*)(w2c0 + DD + 2);                  // 128 KB

    prep_k   <<<WT_NBLK + RS_NBLK + SA_NBLK + 1, 256, 0, stream>>>(
        W, Wt, esrc, row_start, fa, avec, s_a, bias, avec + DD, w2c0);
    gemm_mfma<<<GEMM_NBLK, 256, 0, stream>>>(fb, Wt, bias, w2c0, emb_b, s_b);
    edge_agg8<<<(NA_N + 3) / 4, 256, 0, stream>>>(edst, row_start, s_a,
                                                  s_b, emb_b, out);
}

// Round 17
// 122.544 us; speedup vs baseline: 1.0289x; 1.0289x over previous
//
#include <hip/hip_runtime.h>
#include <cstdint>

#define NA_N 50000
#define NB_N 50000
#define NE_N 800000
#define DD 256
#define GEMM_NBLK 782            // (NB_N+63)/64
#define WT_NBLK   32
#define RS_NBLK   3125           // (NE_N+255)/256
#define SA_NBLK   3125           // (NA_N+15)/16

using bf8   = __attribute__((ext_vector_type(8))) short;   // 8 bf16 = 4 VGPR
using f32x4 = __attribute__((ext_vector_type(4))) float;
using u16x8 = __attribute__((ext_vector_type(8))) ushort;

__device__ __forceinline__ ushort f2bf(float f) {
    uint u = __float_as_uint(f);
    uint r = (u + 0x7fffu + ((u >> 16) & 1u)) >> 16;       // RNE
    return (ushort)r;
}
__device__ __forceinline__ float bf2f(ushort u) {
    return __uint_as_float(((uint)u) << 16);
}

// ------- prep (zero LDS -> full occupancy for streaming blocks) -------
// blocks 0-31:      Wt[n][k] = bf16(W[k][n])
// 32..3156:         row_start[] from sorted esrc
// 3157..6281:       s_a[i] = dot(fa[i,:], a_top)   (51 MB stream at HBM BW)
// 6282:             w2[k] = dot(W[k,:], a_bot) (fp32); c0 = dot(bias, a_bot)
__global__ __launch_bounds__(256) void prep_k(const float* __restrict__ W,
    ushort* __restrict__ Wt, const int* __restrict__ esrc,
    int* __restrict__ row_start, const float* __restrict__ fa,
    const float* __restrict__ a_top, float* __restrict__ s_a,
    const float* __restrict__ bias, const float* __restrict__ a_bot,
    float* __restrict__ w2c0)
{
    const int t = threadIdx.x;
    if (blockIdx.x < WT_NBLK) {                // ---- W transpose+cast, k-slab of 8 ----
        const int k0 = blockIdx.x * 8;
        u16x8 pack;
#pragma unroll
        for (int j = 0; j < 8; j++)
            pack[j] = f2bf(W[(size_t)(k0 + j) * DD + t]);   // coalesced across t
        *(u16x8*)(Wt + (size_t)t * DD + k0) = pack;         // Wt[n=t][k0..k0+7]
        return;
    }
    if (blockIdx.x < WT_NBLK + RS_NBLK) {      // ---- row_start builder ----
        int e = (blockIdx.x - WT_NBLK) * 256 + t;
        if (e >= NE_N) return;
        int s    = esrc[e];
        int prev = (e == 0) ? -1 : esrc[e - 1];
        for (int r = prev + 1; r <= s; r++) row_start[r] = e;
        if (e == NE_N - 1)
            for (int r = s + 1; r <= NA_N; r++) row_start[r] = NE_N;
        return;
    }
    if (blockIdx.x < WT_NBLK + RS_NBLK + SA_NBLK) {  // ---- s_a rowdot ----
        const int row = (blockIdx.x - WT_NBLK - RS_NBLK) * 16 + (t >> 4);
        if (row >= NA_N) return;
        const f32x4* fr = (const f32x4*)(fa + (size_t)row * DD) + (t & 15) * 4;
        const f32x4* tv = (const f32x4*)a_top + (t & 15) * 4;
        float p = 0.f;
#pragma unroll
        for (int j = 0; j < 4; j++) {
            f32x4 x = fr[j], y = tv[j];
            p += x[0] * y[0] + x[1] * y[1] + x[2] * y[2] + x[3] * y[3];
        }
        p += __shfl_xor(p, 1, 64); p += __shfl_xor(p, 2, 64);
        p += __shfl_xor(p, 4, 64); p += __shfl_xor(p, 8, 64);
        if ((t & 15) == 0) s_a[row] = p;
        return;
    }
    // ---- w2[k=t] = dot(W[t,:], a_bot); c0 = dot(bias, a_bot) ----
    {
        const f32x4* wr = (const f32x4*)(W + (size_t)t * DD);
        const f32x4* ab = (const f32x4*)a_bot;
        float acc = 0.f;
#pragma unroll 8
        for (int j = 0; j < 64; j++) {
            f32x4 x = wr[j], y = ab[j];
            acc += x[0] * y[0] + x[1] * y[1] + x[2] * y[2] + x[3] * y[3];
        }
        w2c0[t] = acc;
        if (t == 0) {
            float c0 = 0.f;
            for (int n = 0; n < DD; n++) c0 = fmaf(bias[n], a_bot[n], c0);
            w2c0[DD] = c0;
        }
    }
}

// ------- GEMM BM=64, LDS exactly 32 KB (5 blocks/CU): emb_b = bf16(fb)@W + bias -------
// s_b = fb@w2 + c0 (fp32): per-lane partials pacc[i] accumulated IN the staging loop
// (no cross-lane ops -> the 16 staging loads stay independent/overlapped, fixing r16's
// serialization), then 16 independent 6-level shuffle chains AFTER the loop (16-way ILP).
// As unpadded [64][256] with XOR swizzle (byte ^= (row&7)<<4) on write & read.
// B-frags register-pipelined 1 ks-step ahead.
__global__ __launch_bounds__(256) void gemm_mfma(
    const float* __restrict__ A, const ushort* __restrict__ Wt,
    const float* __restrict__ bias, const float* __restrict__ w2c0,
    ushort* __restrict__ C, float* __restrict__ s_b)
{
    __shared__ ushort As[64 * 256];            // 32768 B exactly
    const int t  = threadIdx.x;
    const int r0 = blockIdx.x * 64;
    const int wv = t >> 6;

    const f32x4 w2v = ((const f32x4*)w2c0)[t & 63];
    const float c0  = w2c0[DD];

    float pacc[16];
#pragma unroll
    for (int i = 0; i < 16; i++) {
        int row = i * 4 + wv;                  // wave-uniform row per iteration
        int c4  = t & 63;
        int gr  = r0 + row; if (gr >= NB_N) gr = 0;       // clamp tail
        float4 v = ((const float4*)(A + (size_t)gr * DD))[c4];
        ushort4 b;
        b.x = f2bf(v.x); b.y = f2bf(v.y); b.z = f2bf(v.z); b.w = f2bf(v.w);
        uint o = (uint)(row * 512 + c4 * 8) ^ (uint)((row & 7) << 4);
        *(ushort4*)((char*)As + o) = b;
        pacc[i] = v.x * w2v[0] + v.y * w2v[1] + v.z * w2v[2] + v.w * w2v[3];
    }
    // deferred s_b reduces: 16 independent chains, lane 0 stores
#pragma unroll
    for (int i = 0; i < 16; i++) {
        float p = pacc[i];
        p += __shfl_xor(p, 1, 64);  p += __shfl_xor(p, 2, 64);
        p += __shfl_xor(p, 4, 64);  p += __shfl_xor(p, 8, 64);
        p += __shfl_xor(p, 16, 64); p += __shfl_xor(p, 32, 64);
        int rowg = r0 + i * 4 + wv;
        if ((t & 63) == 0 && rowg < NB_N) s_b[rowg] = p + c0;
    }
    __syncthreads();

    const int lane = t & 63;
    const int lr   = lane & 15;
    const int lkb  = ((lane >> 4) << 4);       // k-group byte offset within 64B
    const ushort* Wb = Wt + (size_t)(wv * 64 + lr) * DD + (lane >> 4) * 8;

    f32x4 acc[4][4];
#pragma unroll
    for (int m = 0; m < 4; m++)
#pragma unroll
        for (int n = 0; n < 4; n++) acc[m][n] = (f32x4){0.f, 0.f, 0.f, 0.f};

    bf8 bbc[4], bbn[4];
#pragma unroll
    for (int n = 0; n < 4; n++)                       // preload ks=0 B-frags
        bbc[n] = *(const bf8*)(Wb + (size_t)n * 16 * DD);

#pragma unroll
    for (int ks = 0; ks < 8; ks++) {
        if (ks < 7) {
#pragma unroll
            for (int n = 0; n < 4; n++)               // prefetch ks+1 B-frags
                bbn[n] = *(const bf8*)(Wb + (size_t)n * 16 * DD + ks * 32 + 32);
        }
        bf8 af[4];
#pragma unroll
        for (int m = 0; m < 4; m++) {
            int  row = m * 16 + lr;
            uint o   = (uint)(row * 512 + ks * 64 + lkb) ^ (uint)((row & 7) << 4);
            af[m] = *(const bf8*)((const char*)As + o);
        }
#pragma unroll
        for (int m = 0; m < 4; m++)
#pragma unroll
            for (int n = 0; n < 4; n++)
                acc[m][n] = __builtin_amdgcn_mfma_f32_16x16x32_bf16(
                    af[m], bbc[n], acc[m][n], 0, 0, 0);
#pragma unroll
        for (int n = 0; n < 4; n++) bbc[n] = bbn[n];  // static rotation
    }

#pragma unroll
    for (int m = 0; m < 4; m++)
#pragma unroll
        for (int n = 0; n < 4; n++) {
            int   col = wv * 64 + n * 16 + lr;
            float bv  = bias[col];
#pragma unroll
            for (int r = 0; r < 4; r++) {
                int rowg = r0 + m * 16 + (lane >> 4) * 4 + r;  // C: col=lane&15, row=(lane>>4)*4+r
                if (rowg < NB_N)
                    C[(size_t)rowg * DD + col] = f2bf(acc[m][n][r] + bv);
            }
        }
}

// -------- edge aggregation: wave/row, quarter-wave/edge, depth-2 software pipeline --------
__global__ __launch_bounds__(256) void edge_agg8(
    const int* __restrict__ edst, const int* __restrict__ row_start,
    const float* __restrict__ s_a, const float* __restrict__ sb,
    const ushort* __restrict__ emb, float* __restrict__ out)
{
    const int lane = threadIdx.x & 63;
    const int a    = blockIdx.x * 4 + (threadIdx.x >> 6);
    if (a >= NA_N) return;

    const float sa_a = s_a[a];
    const int g = lane >> 4;          // quarter-wave group: one edge per stage
    const int c = lane & 15;          // 16-col block within row
    const int beg = row_start[a], end = row_start[a + 1];

    float accA[8], accB[8];
#pragma unroll
    for (int j = 0; j < 8; j++) { accA[j] = 0.f; accB[j] = 0.f; }
    float rs = 0.f;

    if (beg < end) {
        const int last = end - 1;

        int   pc  = beg + g;                      // current-stage position
        int   pn  = pc + 4;                       // next-stage position
        int   dc  = edst[min(pc, last)];
        int   dn  = edst[min(pn, last)];
        float sbc = sb[dc];
        float sbn = sb[dn];
        const ushort* rc = emb + (size_t)dc * DD + c * 16;
        u16x8 ua = *(const u16x8*)rc;             // stage-0 gathers in flight
        u16x8 ub = *(const u16x8*)(rc + 8);

#pragma unroll 2
        for (int e = beg; e < end; e += 4) {
            // issue next-stage gathers (independent of current consumption)
            const ushort* rn = emb + (size_t)dn * DD + c * 16;
            u16x8 na = *(const u16x8*)rn;
            u16x8 nb = *(const u16x8*)(rn + 8);
            // preload stage+2 index & sb
            int   p2  = pn + 4;
            int   d2  = edst[min(p2, last)];
            float sb2 = sb[d2];

            // score for current stage
            float lg = sa_a + sbc;
            float el = lg > 0.f ? lg : 0.1f * (__expf(lg) - 1.f);
            float s  = (pc < end) ? __expf(el) : 0.f;

            // consume current gathers (waits only on ua/ub — older loads)
#pragma unroll
            for (int j = 0; j < 8; j++) {
                accA[j] = fmaf(s, bf2f(ua[j]), accA[j]);
                accB[j] = fmaf(s, bf2f(ub[j]), accB[j]);
            }
            rs += s;

            // rotate pipeline (pure renaming after unroll)
            pc = pn;  dc = dn;  sbc = sbn;
            ua = na;  ub = nb;
            pn = p2;  dn = d2;  sbn = sb2;
        }
    }

    // combine the 4 quarter-wave partials (xor over group bits 16,32)
#pragma unroll
    for (int j = 0; j < 8; j++) {
        accA[j] += __shfl_xor(accA[j], 16, 64);
        accA[j] += __shfl_xor(accA[j], 32, 64);
        accB[j] += __shfl_xor(accB[j], 16, 64);
        accB[j] += __shfl_xor(accB[j], 32, 64);
    }
    rs += __shfl_xor(rs, 16, 64);
    rs += __shfl_xor(rs, 32, 64);

    if (g == 0) {                      // lanes 0-15 write cols c*16..c*16+15
        const float inv = (rs == 0.f) ? 1.f : (1.f / rs);
        float* op = out + (size_t)a * DD + c * 16;
        float4 o0 = { accA[0] * inv, accA[1] * inv, accA[2] * inv, accA[3] * inv };
        float4 o1 = { accA[4] * inv, accA[5] * inv, accA[6] * inv, accA[7] * inv };
        float4 o2 = { accB[0] * inv, accB[1] * inv, accB[2] * inv, accB[3] * inv };
        float4 o3 = { accB[4] * inv, accB[5] * inv, accB[6] * inv, accB[7] * inv };
        *(float4*)(op + 0)  = o0;
        *(float4*)(op + 4)  = o1;
        *(float4*)(op + 8)  = o2;
        *(float4*)(op + 12) = o3;
    }
}

extern "C" void kernel_launch(void* const* d_in, const int* in_sizes, int n_in,
                              void* d_out, int out_size, void* d_ws, size_t ws_size,
                              hipStream_t stream)
{
    const float* fa   = (const float*)d_in[0];
    const float* fb   = (const float*)d_in[1];
    const float* W    = (const float*)d_in[2];
    const float* bias = (const float*)d_in[3];
    const float* avec = (const float*)d_in[4];
    const int*   esrc = (const int*)d_in[5];
    const int*   edst = (const int*)d_in[6];
    float*       out  = (float*)d_out;

    char*   ws        = (char*)d_ws;
    ushort* emb_b     = (ushort*)ws;                               // 25.6 MB
    float*  s_b       = (float*)(ws + (size_t)NB_N * DD * 2);      // NB
    int*    row_start = (int*)(s_b + NB_N);                        // NA+1
    float*  s_a       = (float*)(row_start + NA_N + 2);            // NA
    float*  w2c0      = s_a + NA_N;                                // 257
    ushort* Wt        = (ushort*)(w2c0 + DD + 2);                  // 128 KB

    prep_k   <<<WT_NBLK + RS_NBLK + SA_NBLK + 1, 256, 0, stream>>>(
        W, Wt, esrc, row_start, fa, avec, s_a, bias, avec + DD, w2c0);
    gemm_mfma<<<GEMM_NBLK, 256, 0, stream>>>(fb, Wt, bias, w2c0, emb_b, s_b);
    edge_agg8<<<(NA_N + 3) / 4, 256, 0, stream>>>(edst, row_start, s_a,
                                                  s_b, emb_b, out);
}

// Round 18
// 105.437 us; speedup vs baseline: 1.1958x; 1.1622x over previous
//
#include <hip/hip_runtime.h>
#include <cstdint>

#define NA_N 50000
#define NB_N 50000
#define NE_N 800000
#define DD 256
#define GEMM_NBLK 782            // (NB_N+63)/64
#define WT_NBLK   32
#define RS_NBLK   3125           // (NE_N+255)/256
#define SA_NBLK   3125           // (NA_N+15)/16

using bf8   = __attribute__((ext_vector_type(8))) short;   // 8 bf16 = 4 VGPR
using f32x4 = __attribute__((ext_vector_type(4))) float;
using u16x8 = __attribute__((ext_vector_type(8))) ushort;

__device__ __forceinline__ ushort f2bf(float f) {
    uint u = __float_as_uint(f);
    uint r = (u + 0x7fffu + ((u >> 16) & 1u)) >> 16;       // RNE
    return (ushort)r;
}
__device__ __forceinline__ float bf2f(ushort u) {
    return __uint_as_float(((uint)u) << 16);
}

// ------- prep (ZERO LDS -> full occupancy for the streaming blocks) -------
// blocks 0-31:        Wt[n][k] = bf16(W[k][n])  (coalesced reads, 16B scattered writes)
// blocks 32..3156:    row_start[] from sorted esrc
// blocks 3157..6281:  s_a[i] = dot(fa[i,:], a_top)  (51 MB stream at HBM BW)
__global__ __launch_bounds__(256) void prep_k(const float* __restrict__ W,
    ushort* __restrict__ Wt, const int* __restrict__ esrc,
    int* __restrict__ row_start, const float* __restrict__ fa,
    const float* __restrict__ a_top, float* __restrict__ s_a)
{
    const int t = threadIdx.x;
    if (blockIdx.x < WT_NBLK) {                // ---- W transpose+cast, k-slab of 8 ----
        const int k0 = blockIdx.x * 8;
        u16x8 pack;
#pragma unroll
        for (int j = 0; j < 8; j++)
            pack[j] = f2bf(W[(size_t)(k0 + j) * DD + t]);   // coalesced across t
        *(u16x8*)(Wt + (size_t)t * DD + k0) = pack;         // Wt[n=t][k0..k0+7]
        return;
    }
    if (blockIdx.x < WT_NBLK + RS_NBLK) {      // ---- row_start builder ----
        int e = (blockIdx.x - WT_NBLK) * 256 + t;
        if (e >= NE_N) return;
        int s    = esrc[e];
        int prev = (e == 0) ? -1 : esrc[e - 1];
        for (int r = prev + 1; r <= s; r++) row_start[r] = e;
        if (e == NE_N - 1)
            for (int r = s + 1; r <= NA_N; r++) row_start[r] = NE_N;
        return;
    }
    // ---- s_a rowdot: 16 rows/block, 16 lanes/row ----
    const int row = (blockIdx.x - WT_NBLK - RS_NBLK) * 16 + (t >> 4);
    if (row >= NA_N) return;
    const f32x4* fr = (const f32x4*)(fa + (size_t)row * DD) + (t & 15) * 4;
    const f32x4* tv = (const f32x4*)a_top + (t & 15) * 4;
    float p = 0.f;
#pragma unroll
    for (int j = 0; j < 4; j++) {
        f32x4 x = fr[j], y = tv[j];
        p += x[0] * y[0] + x[1] * y[1] + x[2] * y[2] + x[3] * y[3];
    }
    p += __shfl_xor(p, 1, 64); p += __shfl_xor(p, 2, 64);
    p += __shfl_xor(p, 4, 64); p += __shfl_xor(p, 8, 64);
    if ((t & 15) == 0) s_a[row] = p;
}

// ------- GEMM BM=64 (r14 measured-best body): emb_b = bf16(fb)@W + bias ; fused s_b -------
// B-frags software-pipelined 1 ks-step ahead; s_b reduced in the EPILOGUE (part/sdot)
// where staging registers are dead — keeps VGPR at 92 (16 waves/CU, matching LDS cap).
__global__ __launch_bounds__(256) void gemm_mfma(
    const float* __restrict__ A, const ushort* __restrict__ Wt,
    const float* __restrict__ bias, const float* __restrict__ a_bot,
    ushort* __restrict__ C, float* __restrict__ s_b)
{
    __shared__ ushort As[64 * 264];
    __shared__ float  sdot[4][64];
    const int t  = threadIdx.x;
    const int r0 = blockIdx.x * 64;

#pragma unroll
    for (int i = 0; i < 16; i++) {
        int flat = i * 256 + t;
        int row  = flat >> 6;
        int c4   = flat & 63;
        int gr   = r0 + row; if (gr >= NB_N) gr = 0;      // clamp tail
        float4 v = ((const float4*)(A + (size_t)gr * DD))[c4];
        ushort4 b;
        b.x = f2bf(v.x); b.y = f2bf(v.y); b.z = f2bf(v.z); b.w = f2bf(v.w);
        *(ushort4*)&As[row * 264 + c4 * 4] = b;
    }
    __syncthreads();

    const int lane = t & 63;
    const int wv   = t >> 6;
    const int lr   = lane & 15;
    const int lk   = (lane >> 4) * 8;
    const ushort* Wb = Wt + (size_t)(wv * 64 + lr) * DD + lk;

    f32x4 acc[4][4];
#pragma unroll
    for (int m = 0; m < 4; m++)
#pragma unroll
        for (int n = 0; n < 4; n++) acc[m][n] = (f32x4){0.f, 0.f, 0.f, 0.f};

    bf8 bbc[4], bbn[4];
#pragma unroll
    for (int n = 0; n < 4; n++)                       // preload ks=0 B-frags
        bbc[n] = *(const bf8*)(Wb + (size_t)n * 16 * DD);

#pragma unroll
    for (int ks = 0; ks < 8; ks++) {
        const int k0 = ks * 32;
        if (ks < 7) {
#pragma unroll
            for (int n = 0; n < 4; n++)               // prefetch ks+1 B-frags
                bbn[n] = *(const bf8*)(Wb + (size_t)n * 16 * DD + k0 + 32);
        }
        bf8 af[4];
#pragma unroll
        for (int m = 0; m < 4; m++)
            af[m] = *(const bf8*)&As[(m * 16 + lr) * 264 + k0 + lk];
#pragma unroll
        for (int m = 0; m < 4; m++)
#pragma unroll
            for (int n = 0; n < 4; n++)
                acc[m][n] = __builtin_amdgcn_mfma_f32_16x16x32_bf16(
                    af[m], bbc[n], acc[m][n], 0, 0, 0);
#pragma unroll
        for (int n = 0; n < 4; n++) bbc[n] = bbn[n];  // static rotation
    }

    float abv[4];
#pragma unroll
    for (int n = 0; n < 4; n++) abv[n] = a_bot[wv * 64 + n * 16 + lr];

    float part[4][4];
#pragma unroll
    for (int m = 0; m < 4; m++)
#pragma unroll
        for (int r = 0; r < 4; r++) part[m][r] = 0.f;

#pragma unroll
    for (int m = 0; m < 4; m++)
#pragma unroll
        for (int n = 0; n < 4; n++) {
            int   col = wv * 64 + n * 16 + lr;
            float bv  = bias[col];
#pragma unroll
            for (int r = 0; r < 4; r++) {
                int   rowg = r0 + m * 16 + (lane >> 4) * 4 + r;  // C: col=lane&15, row=(lane>>4)*4+r
                float v    = acc[m][n][r] + bv;
                if (rowg < NB_N) C[(size_t)rowg * DD + col] = f2bf(v);
                part[m][r] = fmaf(v, abv[n], part[m][r]);
            }
        }

#pragma unroll
    for (int m = 0; m < 4; m++)
#pragma unroll
        for (int r = 0; r < 4; r++) {
#pragma unroll
            for (int off = 1; off < 16; off <<= 1)
                part[m][r] += __shfl_xor(part[m][r], off, 64);
        }
    if (lr == 0) {
#pragma unroll
        for (int m = 0; m < 4; m++)
#pragma unroll
            for (int r = 0; r < 4; r++)
                sdot[wv][m * 16 + (lane >> 4) * 4 + r] = part[m][r];
    }
    __syncthreads();
    if (t < 64) {
        int rowg = r0 + t;
        if (rowg < NB_N)
            s_b[rowg] = sdot[0][t] + sdot[1][t] + sdot[2][t] + sdot[3][t];
    }
}

// -------- edge aggregation: wave/row, quarter-wave/edge, depth-2 software pipeline --------
__global__ __launch_bounds__(256) void edge_agg8(
    const int* __restrict__ edst, const int* __restrict__ row_start,
    const float* __restrict__ s_a, const float* __restrict__ sb,
    const ushort* __restrict__ emb, float* __restrict__ out)
{
    const int lane = threadIdx.x & 63;
    const int a    = blockIdx.x * 4 + (threadIdx.x >> 6);
    if (a >= NA_N) return;

    const float sa_a = s_a[a];
    const int g = lane >> 4;          // quarter-wave group: one edge per stage
    const int c = lane & 15;          // 16-col block within row
    const int beg = row_start[a], end = row_start[a + 1];

    float accA[8], accB[8];
#pragma unroll
    for (int j = 0; j < 8; j++) { accA[j] = 0.f; accB[j] = 0.f; }
    float rs = 0.f;

    if (beg < end) {
        const int last = end - 1;

        int   pc  = beg + g;                      // current-stage position
        int   pn  = pc + 4;                       // next-stage position
        int   dc  = edst[min(pc, last)];
        int   dn  = edst[min(pn, last)];
        float sbc = sb[dc];
        float sbn = sb[dn];
        const ushort* rc = emb + (size_t)dc * DD + c * 16;
        u16x8 ua = *(const u16x8*)rc;             // stage-0 gathers in flight
        u16x8 ub = *(const u16x8*)(rc + 8);

#pragma unroll 2
        for (int e = beg; e < end; e += 4) {
            // issue next-stage gathers (independent of current consumption)
            const ushort* rn = emb + (size_t)dn * DD + c * 16;
            u16x8 na = *(const u16x8*)rn;
            u16x8 nb = *(const u16x8*)(rn + 8);
            // preload stage+2 index & sb
            int   p2  = pn + 4;
            int   d2  = edst[min(p2, last)];
            float sb2 = sb[d2];

            // score for current stage
            float lg = sa_a + sbc;
            float el = lg > 0.f ? lg : 0.1f * (__expf(lg) - 1.f);
            float s  = (pc < end) ? __expf(el) : 0.f;

            // consume current gathers (waits only on ua/ub — older loads)
#pragma unroll
            for (int j = 0; j < 8; j++) {
                accA[j] = fmaf(s, bf2f(ua[j]), accA[j]);
                accB[j] = fmaf(s, bf2f(ub[j]), accB[j]);
            }
            rs += s;

            // rotate pipeline (pure renaming after unroll)
            pc = pn;  dc = dn;  sbc = sbn;
            ua = na;  ub = nb;
            pn = p2;  dn = d2;  sbn = sb2;
        }
    }

    // combine the 4 quarter-wave partials (xor over group bits 16,32)
#pragma unroll
    for (int j = 0; j < 8; j++) {
        accA[j] += __shfl_xor(accA[j], 16, 64);
        accA[j] += __shfl_xor(accA[j], 32, 64);
        accB[j] += __shfl_xor(accB[j], 16, 64);
        accB[j] += __shfl_xor(accB[j], 32, 64);
    }
    rs += __shfl_xor(rs, 16, 64);
    rs += __shfl_xor(rs, 32, 64);

    if (g == 0) {                      // lanes 0-15 write cols c*16..c*16+15
        const float inv = (rs == 0.f) ? 1.f : (1.f / rs);
        float* op = out + (size_t)a * DD + c * 16;
        float4 o0 = { accA[0] * inv, accA[1] * inv, accA[2] * inv, accA[3] * inv };
        float4 o1 = { accA[4] * inv, accA[5] * inv, accA[6] * inv, accA[7] * inv };
        float4 o2 = { accB[0] * inv, accB[1] * inv, accB[2] * inv, accB[3] * inv };
        float4 o3 = { accB[4] * inv, accB[5] * inv, accB[6] * inv, accB[7] * inv };
        *(float4*)(op + 0)  = o0;
        *(float4*)(op + 4)  = o1;
        *(float4*)(op + 8)  = o2;
        *(float4*)(op + 12) = o3;
    }
}

extern "C" void kernel_launch(void* const* d_in, const int* in_sizes, int n_in,
                              void* d_out, int out_size, void* d_ws, size_t ws_size,
                              hipStream_t stream)
{
    const float* fa   = (const float*)d_in[0];
    const float* fb   = (const float*)d_in[1];
    const float* W    = (const float*)d_in[2];
    const float* bias = (const float*)d_in[3];
    const float* avec = (const float*)d_in[4];
    const int*   esrc = (const int*)d_in[5];
    const int*   edst = (const int*)d_in[6];
    float*       out  = (float*)d_out;

    char*   ws        = (char*)d_ws;
    ushort* emb_b     = (ushort*)ws;                               // 25.6 MB
    float*  s_b       = (float*)(ws + (size_t)NB_N * DD * 2);      // NB
    int*    row_start = (int*)(s_b + NB_N);                        // NA+1
    float*  s_a       = (float*)(row_start + NA_N + 2);            // NA
    ushort* Wt        = (ushort*)(s_a + NA_N);                     // 128 KB

    prep_k   <<<WT_NBLK + RS_NBLK + SA_NBLK, 256, 0, stream>>>(
        W, Wt, esrc, row_start, fa, avec, s_a);
    gemm_mfma<<<GEMM_NBLK, 256, 0, stream>>>(fb, Wt, bias, avec + DD,
                                             emb_b, s_b);
    edge_agg8<<<(NA_N + 3) / 4, 256, 0, stream>>>(edst, row_start, s_a,
                                                  s_b, emb_b, out);
}

// Round 19
// 105.105 us; speedup vs baseline: 1.1996x; 1.0032x over previous
//
#include <hip/hip_runtime.h>
#include <cstdint>

#define NA_N 50000
#define NB_N 50000
#define NE_N 800000
#define DD 256
#define GEMM_NBLK 782            // (NB_N+63)/64
#define WT_NBLK   32
#define RS_NBLK   3125           // (NE_N+255)/256
#define SA_NBLK   3125           // (NA_N+15)/16

using bf8   = __attribute__((ext_vector_type(8))) short;   // 8 bf16 = 4 VGPR
using f32x4 = __attribute__((ext_vector_type(4))) float;
using u16x8 = __attribute__((ext_vector_type(8))) ushort;

__device__ __forceinline__ ushort f2bf(float f) {
    uint u = __float_as_uint(f);
    uint r = (u + 0x7fffu + ((u >> 16) & 1u)) >> 16;       // RNE
    return (ushort)r;
}
__device__ __forceinline__ float bf2f(ushort u) {
    return __uint_as_float(((uint)u) << 16);
}

// ------- prep (ZERO LDS -> full occupancy for the streaming blocks) -------
__global__ __launch_bounds__(256) void prep_k(const float* __restrict__ W,
    ushort* __restrict__ Wt, const int* __restrict__ esrc,
    int* __restrict__ row_start, const float* __restrict__ fa,
    const float* __restrict__ a_top, float* __restrict__ s_a)
{
    const int t = threadIdx.x;
    if (blockIdx.x < WT_NBLK) {                // ---- W transpose+cast, k-slab of 8 ----
        const int k0 = blockIdx.x * 8;
        u16x8 pack;
#pragma unroll
        for (int j = 0; j < 8; j++)
            pack[j] = f2bf(W[(size_t)(k0 + j) * DD + t]);   // coalesced across t
        *(u16x8*)(Wt + (size_t)t * DD + k0) = pack;         // Wt[n=t][k0..k0+7]
        return;
    }
    if (blockIdx.x < WT_NBLK + RS_NBLK) {      // ---- row_start builder ----
        int e = (blockIdx.x - WT_NBLK) * 256 + t;
        if (e >= NE_N) return;
        int s    = esrc[e];
        int prev = (e == 0) ? -1 : esrc[e - 1];
        for (int r = prev + 1; r <= s; r++) row_start[r] = e;
        if (e == NE_N - 1)
            for (int r = s + 1; r <= NA_N; r++) row_start[r] = NE_N;
        return;
    }
    // ---- s_a rowdot: 16 rows/block, 16 lanes/row ----
    const int row = (blockIdx.x - WT_NBLK - RS_NBLK) * 16 + (t >> 4);
    if (row >= NA_N) return;
    const f32x4* fr = (const f32x4*)(fa + (size_t)row * DD) + (t & 15) * 4;
    const f32x4* tv = (const f32x4*)a_top + (t & 15) * 4;
    float p = 0.f;
#pragma unroll
    for (int j = 0; j < 4; j++) {
        f32x4 x = fr[j], y = tv[j];
        p += x[0] * y[0] + x[1] * y[1] + x[2] * y[2] + x[3] * y[3];
    }
    p += __shfl_xor(p, 1, 64); p += __shfl_xor(p, 2, 64);
    p += __shfl_xor(p, 4, 64); p += __shfl_xor(p, 8, 64);
    if ((t & 15) == 0) s_a[row] = p;
}

// ------- GEMM BM=64: r14 body + LDS shrunk to exactly 32 KB -> 5 blocks/CU -------
// As unpadded [64][256] with XOR swizzle byte ^= (row&7)<<4 (proven r16/r17);
// sdot ALIASED into As after the MFMA loop (As is dead then; extra barrier).
// VGPR unchanged (~92, permits 5 blocks); B-frags register-pipelined 1 ks ahead.
__global__ __launch_bounds__(256) void gemm_mfma(
    const float* __restrict__ A, const ushort* __restrict__ Wt,
    const float* __restrict__ bias, const float* __restrict__ a_bot,
    ushort* __restrict__ C, float* __restrict__ s_b)
{
    __shared__ ushort As[64 * 256];            // 32768 B exactly; reused as sdot later
    const int t  = threadIdx.x;
    const int r0 = blockIdx.x * 64;

#pragma unroll
    for (int i = 0; i < 16; i++) {
        int flat = i * 256 + t;
        int row  = flat >> 6;
        int c4   = flat & 63;
        int gr   = r0 + row; if (gr >= NB_N) gr = 0;      // clamp tail
        float4 v = ((const float4*)(A + (size_t)gr * DD))[c4];
        ushort4 b;
        b.x = f2bf(v.x); b.y = f2bf(v.y); b.z = f2bf(v.z); b.w = f2bf(v.w);
        uint o = (uint)(row * 512 + c4 * 8) ^ (uint)((row & 7) << 4);
        *(ushort4*)((char*)As + o) = b;
    }
    __syncthreads();

    const int lane = t & 63;
    const int wv   = t >> 6;
    const int lr   = lane & 15;
    const int lkb  = (lane >> 4) * 16;         // k-group byte offset within 64B row-chunk
    const ushort* Wb = Wt + (size_t)(wv * 64 + lr) * DD + (lane >> 4) * 8;

    f32x4 acc[4][4];
#pragma unroll
    for (int m = 0; m < 4; m++)
#pragma unroll
        for (int n = 0; n < 4; n++) acc[m][n] = (f32x4){0.f, 0.f, 0.f, 0.f};

    bf8 bbc[4], bbn[4];
#pragma unroll
    for (int n = 0; n < 4; n++)                       // preload ks=0 B-frags
        bbc[n] = *(const bf8*)(Wb + (size_t)n * 16 * DD);

#pragma unroll
    for (int ks = 0; ks < 8; ks++) {
        if (ks < 7) {
#pragma unroll
            for (int n = 0; n < 4; n++)               // prefetch ks+1 B-frags
                bbn[n] = *(const bf8*)(Wb + (size_t)n * 16 * DD + ks * 32 + 32);
        }
        bf8 af[4];
#pragma unroll
        for (int m = 0; m < 4; m++) {
            int  row = m * 16 + lr;
            uint o   = (uint)(row * 512 + ks * 64 + lkb) ^ (uint)((row & 7) << 4);
            af[m] = *(const bf8*)((const char*)As + o);
        }
#pragma unroll
        for (int m = 0; m < 4; m++)
#pragma unroll
            for (int n = 0; n < 4; n++)
                acc[m][n] = __builtin_amdgcn_mfma_f32_16x16x32_bf16(
                    af[m], bbc[n], acc[m][n], 0, 0, 0);
#pragma unroll
        for (int n = 0; n < 4; n++) bbc[n] = bbn[n];  // static rotation
    }

    float abv[4];
#pragma unroll
    for (int n = 0; n < 4; n++) abv[n] = a_bot[wv * 64 + n * 16 + lr];

    float part[4][4];
#pragma unroll
    for (int m = 0; m < 4; m++)
#pragma unroll
        for (int r = 0; r < 4; r++) part[m][r] = 0.f;

#pragma unroll
    for (int m = 0; m < 4; m++)
#pragma unroll
        for (int n = 0; n < 4; n++) {
            int   col = wv * 64 + n * 16 + lr;
            float bv  = bias[col];
#pragma unroll
            for (int r = 0; r < 4; r++) {
                int   rowg = r0 + m * 16 + (lane >> 4) * 4 + r;  // C: col=lane&15, row=(lane>>4)*4+r
                float v    = acc[m][n][r] + bv;
                if (rowg < NB_N) C[(size_t)rowg * DD + col] = f2bf(v);
                part[m][r] = fmaf(v, abv[n], part[m][r]);
            }
        }

#pragma unroll
    for (int m = 0; m < 4; m++)
#pragma unroll
        for (int r = 0; r < 4; r++) {
#pragma unroll
            for (int off = 1; off < 16; off <<= 1)
                part[m][r] += __shfl_xor(part[m][r], off, 64);
        }

    __syncthreads();                           // all As reads done -> safe to alias
    float* sdot = (float*)As;                  // [4][64] floats = 1 KB inside As
    if (lr == 0) {
#pragma unroll
        for (int m = 0; m < 4; m++)
#pragma unroll
            for (int r = 0; r < 4; r++)
                sdot[wv * 64 + m * 16 + (lane >> 4) * 4 + r] = part[m][r];
    }
    __syncthreads();
    if (t < 64) {
        int rowg = r0 + t;
        if (rowg < NB_N)
            s_b[rowg] = sdot[0 * 64 + t] + sdot[1 * 64 + t] +
                        sdot[2 * 64 + t] + sdot[3 * 64 + t];
    }
}

// -------- edge aggregation: wave/row, quarter-wave/edge, depth-2 software pipeline --------
__global__ __launch_bounds__(256) void edge_agg8(
    const int* __restrict__ edst, const int* __restrict__ row_start,
    const float* __restrict__ s_a, const float* __restrict__ sb,
    const ushort* __restrict__ emb, float* __restrict__ out)
{
    const int lane = threadIdx.x & 63;
    const int a    = blockIdx.x * 4 + (threadIdx.x >> 6);
    if (a >= NA_N) return;

    const float sa_a = s_a[a];
    const int g = lane >> 4;          // quarter-wave group: one edge per stage
    const int c = lane & 15;          // 16-col block within row
    const int beg = row_start[a], end = row_start[a + 1];

    float accA[8], accB[8];
#pragma unroll
    for (int j = 0; j < 8; j++) { accA[j] = 0.f; accB[j] = 0.f; }
    float rs = 0.f;

    if (beg < end) {
        const int last = end - 1;

        int   pc  = beg + g;                      // current-stage position
        int   pn  = pc + 4;                       // next-stage position
        int   dc  = edst[min(pc, last)];
        int   dn  = edst[min(pn, last)];
        float sbc = sb[dc];
        float sbn = sb[dn];
        const ushort* rc = emb + (size_t)dc * DD + c * 16;
        u16x8 ua = *(const u16x8*)rc;             // stage-0 gathers in flight
        u16x8 ub = *(const u16x8*)(rc + 8);

#pragma unroll 2
        for (int e = beg; e < end; e += 4) {
            // issue next-stage gathers (independent of current consumption)
            const ushort* rn = emb + (size_t)dn * DD + c * 16;
            u16x8 na = *(const u16x8*)rn;
            u16x8 nb = *(const u16x8*)(rn + 8);
            // preload stage+2 index & sb
            int   p2  = pn + 4;
            int   d2  = edst[min(p2, last)];
            float sb2 = sb[d2];

            // score for current stage
            float lg = sa_a + sbc;
            float el = lg > 0.f ? lg : 0.1f * (__expf(lg) - 1.f);
            float s  = (pc < end) ? __expf(el) : 0.f;

            // consume current gathers (waits only on ua/ub — older loads)
#pragma unroll
            for (int j = 0; j < 8; j++) {
                accA[j] = fmaf(s, bf2f(ua[j]), accA[j]);
                accB[j] = fmaf(s, bf2f(ub[j]), accB[j]);
            }
            rs += s;

            // rotate pipeline (pure renaming after unroll)
            pc = pn;  dc = dn;  sbc = sbn;
            ua = na;  ub = nb;
            pn = p2;  dn = d2;  sbn = sb2;
        }
    }

    // combine the 4 quarter-wave partials (xor over group bits 16,32)
#pragma unroll
    for (int j = 0; j < 8; j++) {
        accA[j] += __shfl_xor(accA[j], 16, 64);
        accA[j] += __shfl_xor(accA[j], 32, 64);
        accB[j] += __shfl_xor(accB[j], 16, 64);
        accB[j] += __shfl_xor(accB[j], 32, 64);
    }
    rs += __shfl_xor(rs, 16, 64);
    rs += __shfl_xor(rs, 32, 64);

    if (g == 0) {                      // lanes 0-15 write cols c*16..c*16+15
        const float inv = (rs == 0.f) ? 1.f : (1.f / rs);
        float* op = out + (size_t)a * DD + c * 16;
        float4 o0 = { accA[0] * inv, accA[1] * inv, accA[2] * inv, accA[3] * inv };
        float4 o1 = { accA[4] * inv, accA[5] * inv, accA[6] * inv, accA[7] * inv };
        float4 o2 = { accB[0] * inv, accB[1] * inv, accB[2] * inv, accB[3] * inv };
        float4 o3 = { accB[4] * inv, accB[5] * inv, accB[6] * inv, accB[7] * inv };
        *(float4*)(op + 0)  = o0;
        *(float4*)(op + 4)  = o1;
        *(float4*)(op + 8)  = o2;
        *(float4*)(op + 12) = o3;
    }
}

extern "C" void kernel_launch(void* const* d_in, const int* in_sizes, int n_in,
                              void* d_out, int out_size, void* d_ws, size_t ws_size,
                              hipStream_t stream)
{
    const float* fa   = (const float*)d_in[0];
    const float* fb   = (const float*)d_in[1];
    const float* W    = (const float*)d_in[2];
    const float* bias = (const float*)d_in[3];
    const float* avec = (const float*)d_in[4];
    const int*   esrc = (const int*)d_in[5];
    const int*   edst = (const int*)d_in[6];
    float*       out  = (float*)d_out;

    char*   ws        = (char*)d_ws;
    ushort* emb_b     = (ushort*)ws;                               // 25.6 MB
    float*  s_b       = (float*)(ws + (size_t)NB_N * DD * 2);      // NB
    int*    row_start = (int*)(s_b + NB_N);                        // NA+1
    float*  s_a       = (float*)(row_start + NA_N + 2);            // NA
    ushort* Wt        = (ushort*)(s_a + NA_N);                     // 128 KB

    prep_k   <<<WT_NBLK + RS_NBLK + SA_NBLK, 256, 0, stream>>>(
        W, Wt, esrc, row_start, fa, avec, s_a);
    gemm_mfma<<<GEMM_NBLK, 256, 0, stream>>>(fb, Wt, bias, avec + DD,
                                             emb_b, s_b);
    edge_agg8<<<(NA_N + 3) / 4, 256, 0, stream>>>(edst, row_start, s_a,
                                                  s_b, emb_b, out);
}